// Round 3
// baseline (88.388 us; speedup 1.0000x reference)
//
#include <hip/hip_runtime.h>
#include <hip/hip_bf16.h>

namespace {

constexpr int Bsz = 64, Cch = 3, Himg = 224, Wimg = 224, Ppat = 16;
constexpr int Dm = 768, NPW = 14, NPATCH = 196, SEQn = 197;
constexpr int Mtot = Bsz * NPATCH;   // 12544
constexpr int Ktot = 768, Ntot = 768;
constexpr int BM = 64, BN = 128, BK = 64;
constexpr int MT = Mtot / BM;        // 196
constexpr int NT = Ntot / BN;        // 6
constexpr int KT = Ktot / BK;        // 12
constexpr int NBLK = MT * NT;        // 1176 (divisible by 8)
constexpr int TILE_A = BM * BK;      // 4096 bf16 = 8 KB
constexpr int TILE_B = BN * BK;      // 8192 bf16 = 16 KB
constexpr int EPAD = 136;            // epilogue fp32 row pitch (544B, 16B-aligned)

typedef __attribute__((ext_vector_type(8))) short bf16x8;
typedef __attribute__((ext_vector_type(4))) float f32x4;

__device__ inline unsigned short f2bf(float f) {
  __bf16 h = (__bf16)f;  // RNE; clang fuses pairs into v_cvt_pk_bf16_f32
  union { __bf16 h; unsigned short u; } c;
  c.h = h;
  return c.u;
}

// ---------------- prepass: W fp32 [K][N] -> bf16 swizzled tiles, + cls row --
// W tile image: tile (nb, kt), element (n', k') at flat index
//   (nb*KT + kt)*TILE_B + ((n'*BK + k') ^ ((n'&7) << 3))
// so a LINEAR global_load_lds stage yields the XOR-swizzled LDS image (m173).
__global__ void prep_kernel(const float* __restrict__ W, unsigned short* __restrict__ Wt,
                            const float* __restrict__ pos, const float* __restrict__ cls,
                            float* __restrict__ out) {
  int bid = blockIdx.x;
  if (bid < (Ktot / 8) * Ntot / 256) {  // 288 blocks: W prep
    int cid = bid * 256 + threadIdx.x;
    int kc = cid / Ntot;                // k-chunk of 8 (0..95)
    int n = cid - kc * Ntot;
    int nb = n >> 7;
    int np = n & 127;
    int kt = kc >> 3;
    int k8 = (kc & 7) * 8;
    unsigned short tmp[8];
#pragma unroll
    for (int j = 0; j < 8; ++j) tmp[j] = f2bf(W[(kc * 8 + j) * Ntot + n]);
    int idx = np * BK + k8;
    int sidx = idx ^ ((np & 7) << 3);
    unsigned short* dst = Wt + (nb * KT + kt) * TILE_B + sidx;
    *reinterpret_cast<ushort4*>(dst + 0) = make_ushort4(tmp[0], tmp[1], tmp[2], tmp[3]);
    *reinterpret_cast<ushort4*>(dst + 4) = make_ushort4(tmp[4], tmp[5], tmp[6], tmp[7]);
  } else {  // 192 blocks: class-token row (s = 0)
    int i = (bid - (Ktot / 8) * Ntot / 256) * 256 + threadIdx.x;  // 0..64*768-1
    int b = i / Dm;
    int d = i - b * Dm;
    out[b * (SEQn * Dm) + d] = cls[d] + pos[d];
  }
}

// ---------------- main GEMM: 64x128 tile, 8 waves, counted-vmcnt pipeline ---
__global__ __launch_bounds__(512, 6)
void gemm_kernel(const float* __restrict__ x, const unsigned short* __restrict__ Wt,
                 const float* __restrict__ bias, const float* __restrict__ pos,
                 float* __restrict__ out) {
  __shared__ union SMem {
    struct { unsigned short A[2][TILE_A]; unsigned short B[2][TILE_B]; } t;  // 48 KB
    float ep[BM][EPAD];                                                      // 34 KB
  } sm;

  // XCD-chunked bijective swizzle (NBLK % 8 == 0): bn varies fastest within a
  // chunk -> A-panel reused 6x within one XCD's L2.
  const int orig = blockIdx.x;
  const int wg = (orig & 7) * (NBLK / 8) + (orig >> 3);
  const int bm = wg / NT;
  const int bn = wg - bm * NT;

  const int t = threadIdx.x;
  const int lane = t & 63;
  const int wid = t >> 6;              // 8 waves: 2 (M) x 4 (N)
  const int wr = wid >> 2, wc = wid & 3;
  const int fr = lane & 15, fq = lane >> 4;

  // A staging geometry: thread covers float4 k-group c4, rows r0 and r0+32
  const int c4 = t & 15;
  const int r0 = t >> 4;
  int a_base[2];
#pragma unroll
  for (int i = 0; i < 2; ++i) {
    int m = bm * BM + r0 + 32 * i;
    int b = m / NPATCH;
    int pidx = m - b * NPATCH;
    int ph = pidx / NPW;
    int pw = pidx - ph * NPW;
    a_base[i] = ((b * Cch) * Himg + ph * Ppat) * Wimg + pw * Ppat;
  }
  const unsigned short* wt_base = Wt + bn * (KT * TILE_B);

  auto LOADA = [&](int kt, float4 (&av)[2]) {  // issue global loads (regs)
    int kg = kt * BK + c4 * 4;
    int c = kg >> 8;
    int pi = (kg >> 4) & 15;
    int pj = kg & 15;
    int off = (c * Himg + pi) * Wimg + pj;
#pragma unroll
    for (int i = 0; i < 2; ++i)
      av[i] = *reinterpret_cast<const float4*>(x + a_base[i] + off);
  };
  auto WRITEA = [&](int buf, float4 (&av)[2]) {  // convert + swizzled ds_write
#pragma unroll
    for (int i = 0; i < 2; ++i) {
      int row = r0 + 32 * i;
      int idx = (row * BK + c4 * 4) ^ ((row & 7) << 3);
      ushort4 pk = make_ushort4(f2bf(av[i].x), f2bf(av[i].y), f2bf(av[i].z), f2bf(av[i].w));
      *reinterpret_cast<ushort4*>(&sm.t.A[buf][idx]) = pk;
    }
  };
  auto STAGEB = [&](int buf, int kt) {  // async, linear dest (pre-swizzled src)
    const unsigned short* src = wt_base + kt * TILE_B + t * 8;
#pragma unroll
    for (int i = 0; i < 2; ++i) {
      __builtin_amdgcn_global_load_lds(
          (const __attribute__((address_space(1))) unsigned int*)(src + i * 4096),
          (__attribute__((address_space(3))) unsigned int*)(&sm.t.B[buf][t * 8 + i * 4096]),
          16, 0, 0);
    }
  };

  f32x4 acc[2][2];
#pragma unroll
  for (int mi = 0; mi < 2; ++mi)
#pragma unroll
    for (int ni = 0; ni < 2; ++ni) acc[mi][ni] = {0.f, 0.f, 0.f, 0.f};

  auto MFMA = [&](int cur) {
#pragma unroll
    for (int ks = 0; ks < 2; ++ks) {
      bf16x8 af[2], bfr[2];
#pragma unroll
      for (int mi = 0; mi < 2; ++mi) {
        int row = wr * 32 + mi * 16 + fr;
        int idx = (row * BK + ks * 32 + fq * 8) ^ ((row & 7) << 3);
        af[mi] = *reinterpret_cast<const bf16x8*>(&sm.t.A[cur][idx]);
      }
#pragma unroll
      for (int ni = 0; ni < 2; ++ni) {
        int n = wc * 32 + ni * 16 + fr;
        int idx = (n * BK + ks * 32 + fq * 8) ^ ((n & 7) << 3);
        bfr[ni] = *reinterpret_cast<const bf16x8*>(&sm.t.B[cur][idx]);
      }
#pragma unroll
      for (int mi = 0; mi < 2; ++mi)
#pragma unroll
        for (int ni = 0; ni < 2; ++ni)
          acc[mi][ni] = __builtin_amdgcn_mfma_f32_16x16x32_bf16(
              af[mi], bfr[ni], acc[mi][ni], 0, 0, 0);
    }
  };

  float4 avA[2], avB[2];

  // ---- prologue: stage tile 0; leave A(1) loads in flight across barrier
  LOADA(0, avA);                       // FIFO: A0 first
  __builtin_amdgcn_sched_barrier(0);
  STAGEB(0, 0);                        // then B0
  __builtin_amdgcn_sched_barrier(0);
  WRITEA(0, avA);                      // waits A0 (vmcnt keeps B0 in flight)
  LOADA(1, avA);                       // refill avA with kt=1 data
  asm volatile("s_waitcnt vmcnt(2) lgkmcnt(0)" ::: "memory");  // drain B0, keep A1
  __builtin_amdgcn_s_barrier();
  __builtin_amdgcn_sched_barrier(0);

  // ---- steady loop: per iter issue B(kt+1) then A(kt+2); end-of-iter wait
  // drains only B (older), A(kt+2) stays in flight across the barrier.
  auto KSTEP = [&](int kt, int cur, float4 (&avNear)[2], float4 (&avFar)[2]) {
    const bool haveNext = (kt + 1 < KT);
    const bool haveFar = (kt + 2 < KT);
    if (haveNext) STAGEB(cur ^ 1, kt + 1);
    __builtin_amdgcn_sched_barrier(0);  // pin FIFO order: B before A
    if (haveFar) LOADA(kt + 2, avFar);
    MFMA(cur);
    if (haveNext) WRITEA(cur ^ 1, avNear);  // compiler waits avNear only
    if (haveFar) {
      asm volatile("s_waitcnt vmcnt(2) lgkmcnt(0)" ::: "memory");
    } else {
      asm volatile("s_waitcnt vmcnt(0) lgkmcnt(0)" ::: "memory");
    }
    __builtin_amdgcn_s_barrier();
    __builtin_amdgcn_sched_barrier(0);
  };
  for (int kt = 0; kt < KT; kt += 2) {
    KSTEP(kt, 0, avA, avB);
    KSTEP(kt + 1, 1, avB, avA);
  }

  // ---- epilogue: transpose through LDS -> full-cacheline stores ----------
  // dump acc into padded fp32 tile (row pitch 136 floats spreads banks)
#pragma unroll
  for (int mi = 0; mi < 2; ++mi)
#pragma unroll
    for (int ni = 0; ni < 2; ++ni)
#pragma unroll
      for (int j = 0; j < 4; ++j)
        sm.ep[wr * 32 + mi * 16 + fq * 4 + j][wc * 32 + ni * 16 + fr] = acc[mi][ni][j];
  __syncthreads();

  {
    const int r = t >> 3, u = t & 7;   // 8 threads per row, 16 floats each
    const int m = bm * BM + r;
    const int b = m / NPATCH;
    const int s = m - b * NPATCH + 1;  // +1: class token at s=0
    const int n0 = bn * BN + u * 16;
    const float* brow = bias + n0;
    const float* prow = pos + s * Dm + n0;
    float* orow = out + (b * SEQn + s) * Dm + n0;
#pragma unroll
    for (int i = 0; i < 4; ++i) {
      float4 v = *reinterpret_cast<const float4*>(&sm.ep[r][u * 16 + i * 4]);
      float4 bb = *reinterpret_cast<const float4*>(brow + i * 4);
      float4 pp = *reinterpret_cast<const float4*>(prow + i * 4);
      v.x += bb.x + pp.x; v.y += bb.y + pp.y; v.z += bb.z + pp.z; v.w += bb.w + pp.w;
      *reinterpret_cast<float4*>(orow + i * 4) = v;
    }
  }
}

}  // namespace

extern "C" void kernel_launch(void* const* d_in, const int* in_sizes, int n_in,
                              void* d_out, int out_size, void* d_ws, size_t ws_size,
                              hipStream_t stream) {
  const float* x = (const float*)d_in[0];
  const float* W = (const float*)d_in[1];
  const float* bias = (const float*)d_in[2];
  const float* pos = (const float*)d_in[3];
  const float* cls = (const float*)d_in[4];
  float* out = (float*)d_out;
  unsigned short* Wt = (unsigned short*)d_ws;  // 768*768*2 = 1.18 MB

  prep_kernel<<<(Ktot / 8) * Ntot / 256 + Bsz * Dm / 256, 256, 0, stream>>>(W, Wt, pos, cls, out);
  gemm_kernel<<<NBLK, 512, 0, stream>>>(x, Wt, bias, pos, out);
}

// Round 4
// 81.156 us; speedup vs baseline: 1.0891x; 1.0891x over previous
//
#include <hip/hip_runtime.h>
#include <hip/hip_bf16.h>

namespace {

constexpr int Bsz = 64, Cch = 3, Himg = 224, Wimg = 224, Ppat = 16;
constexpr int Dm = 768, NPW = 14, NPATCH = 196, SEQn = 197;
constexpr int Mtot = Bsz * NPATCH;   // 12544
constexpr int Ktot = 768, Ntot = 768;
constexpr int BM = 64, BN = 64, BK = 64;
constexpr int MT = Mtot / BM;        // 196
constexpr int NT = Ntot / BN;        // 12
constexpr int KT = Ktot / BK;        // 12
constexpr int NBLK = MT * NT;        // 2352 (divisible by 8)
constexpr int TILE_A = BM * BK;      // 4096 bf16 = 8 KB
constexpr int TILE_B = BN * BK;      // 4096 bf16 = 8 KB
constexpr int EPAD = 68;             // epilogue fp32 row pitch

typedef __attribute__((ext_vector_type(8))) short bf16x8;
typedef __attribute__((ext_vector_type(4))) float f32x4;

__device__ inline unsigned short f2bf(float f) {
  __bf16 h = (__bf16)f;  // RNE; clang fuses pairs into v_cvt_pk_bf16_f32
  union { __bf16 h; unsigned short u; } c;
  c.h = h;
  return c.u;
}

// ---------------- prepass: W fp32 [K][N] -> bf16 swizzled tiles, + cls row --
// W tile image: tile (nb, kt), element (n', k') at flat index
//   (nb*KT + kt)*TILE_B + ((n'*BK + k') ^ ((n'&7) << 3))
// so a LINEAR global_load_lds stage yields the XOR-swizzled LDS image (m173).
__global__ void prep_kernel(const float* __restrict__ W, unsigned short* __restrict__ Wt,
                            const float* __restrict__ pos, const float* __restrict__ cls,
                            float* __restrict__ out) {
  int bid = blockIdx.x;
  if (bid < (Ktot / 8) * Ntot / 256) {  // 288 blocks: W prep
    int cid = bid * 256 + threadIdx.x;
    int kc = cid / Ntot;                // k-chunk of 8 (0..95)
    int n = cid - kc * Ntot;
    int nb = n >> 6;                    // 0..11
    int np = n & 63;
    int kt = kc >> 3;
    int k8 = (kc & 7) * 8;
    unsigned short tmp[8];
#pragma unroll
    for (int j = 0; j < 8; ++j) tmp[j] = f2bf(W[(kc * 8 + j) * Ntot + n]);
    int idx = np * BK + k8;
    int sidx = idx ^ ((np & 7) << 3);
    unsigned short* dst = Wt + (nb * KT + kt) * TILE_B + sidx;
    *reinterpret_cast<ushort4*>(dst + 0) = make_ushort4(tmp[0], tmp[1], tmp[2], tmp[3]);
    *reinterpret_cast<ushort4*>(dst + 4) = make_ushort4(tmp[4], tmp[5], tmp[6], tmp[7]);
  } else {  // 192 blocks: class-token row (s = 0)
    int i = (bid - (Ktot / 8) * Ntot / 256) * 256 + threadIdx.x;  // 0..64*768-1
    int b = i / Dm;
    int d = i - b * Dm;
    out[b * (SEQn * Dm) + d] = cls[d] + pos[d];
  }
}

// ---------------- main GEMM: 64x64 tile, 4 waves, 2-phase dbuf (compiler-scheduled)
__global__ __launch_bounds__(256, 5)
void gemm_kernel(const float* __restrict__ x, const unsigned short* __restrict__ Wt,
                 const float* __restrict__ bias, const float* __restrict__ pos,
                 float* __restrict__ out) {
  __shared__ union SMem {
    struct { unsigned short A[2][TILE_A]; unsigned short B[2][TILE_B]; } t;  // 32 KB
    float ep[BM][EPAD];                                                      // 17.4 KB
  } sm;

  // XCD-chunked bijective swizzle (NBLK % 8 == 0): bn varies fastest within a
  // chunk -> x panel for one bm reused 12x within one XCD's L2.
  const int orig = blockIdx.x;
  const int wg = (orig & 7) * (NBLK / 8) + (orig >> 3);
  const int bm = wg / NT;
  const int bn = wg - bm * NT;

  const int t = threadIdx.x;
  const int lane = t & 63;
  const int wid = t >> 6;              // 4 waves: 2 (M) x 2 (N)
  const int wr = wid >> 1, wc = wid & 1;
  const int fr = lane & 15, fq = lane >> 4;

  // A staging: thread covers float4 k-group c4, rows r0 + 16*i (i<4)
  const int c4 = t & 15;
  const int r0 = t >> 4;
  int a_base[4];
#pragma unroll
  for (int i = 0; i < 4; ++i) {
    int m = bm * BM + r0 + 16 * i;
    int b = m / NPATCH;
    int pidx = m - b * NPATCH;
    int ph = pidx / NPW;
    int pw = pidx - ph * NPW;
    a_base[i] = ((b * Cch) * Himg + ph * Ppat) * Wimg + pw * Ppat;
  }
  const unsigned short* wt_base = Wt + bn * (KT * TILE_B);

  float4 av[4];
  auto LOADA = [&](int kt) {  // issue global loads early
    int kg = kt * BK + c4 * 4;
    int c = kg >> 8;
    int pi = (kg >> 4) & 15;
    int pj = kg & 15;
    int off = (c * Himg + pi) * Wimg + pj;
#pragma unroll
    for (int i = 0; i < 4; ++i)
      av[i] = *reinterpret_cast<const float4*>(x + a_base[i] + off);
  };
  auto WRITEA = [&](int buf) {  // convert + swizzled ds_write (late)
#pragma unroll
    for (int i = 0; i < 4; ++i) {
      int row = r0 + 16 * i;
      int idx = (row * BK + c4 * 4) ^ ((row & 7) << 3);
      ushort4 pk = make_ushort4(f2bf(av[i].x), f2bf(av[i].y), f2bf(av[i].z), f2bf(av[i].w));
      *reinterpret_cast<ushort4*>(&sm.t.A[buf][idx]) = pk;
    }
  };
  auto STAGEB = [&](int buf, int kt) {  // async, linear dest (pre-swizzled src)
    const unsigned short* src = wt_base + kt * TILE_B + t * 8;
#pragma unroll
    for (int i = 0; i < 2; ++i) {
      __builtin_amdgcn_global_load_lds(
          (const __attribute__((address_space(1))) unsigned int*)(src + i * 2048),
          (__attribute__((address_space(3))) unsigned int*)(&sm.t.B[buf][t * 8 + i * 2048]),
          16, 0, 0);
    }
  };

  f32x4 acc[2][2];
#pragma unroll
  for (int mi = 0; mi < 2; ++mi)
#pragma unroll
    for (int ni = 0; ni < 2; ++ni) acc[mi][ni] = {0.f, 0.f, 0.f, 0.f};

  // prologue: stage tile 0
  LOADA(0);
  STAGEB(0, 0);
  WRITEA(0);
  __syncthreads();

  for (int kt = 0; kt < KT; ++kt) {
    const int cur = kt & 1, nxt = cur ^ 1;
    if (kt + 1 < KT) {
      LOADA(kt + 1);        // next A -> regs (latency hides under MFMA)
      STAGEB(nxt, kt + 1);  // next B -> LDS (async)
    }
#pragma unroll
    for (int ks = 0; ks < 2; ++ks) {
      bf16x8 af[2], bfr[2];
#pragma unroll
      for (int mi = 0; mi < 2; ++mi) {
        int row = wr * 32 + mi * 16 + fr;
        int idx = (row * BK + ks * 32 + fq * 8) ^ ((row & 7) << 3);
        af[mi] = *reinterpret_cast<const bf16x8*>(&sm.t.A[cur][idx]);
      }
#pragma unroll
      for (int ni = 0; ni < 2; ++ni) {
        int n = wc * 32 + ni * 16 + fr;
        int idx = (n * BK + ks * 32 + fq * 8) ^ ((n & 7) << 3);
        bfr[ni] = *reinterpret_cast<const bf16x8*>(&sm.t.B[cur][idx]);
      }
#pragma unroll
      for (int mi = 0; mi < 2; ++mi)
#pragma unroll
        for (int ni = 0; ni < 2; ++ni)
          acc[mi][ni] = __builtin_amdgcn_mfma_f32_16x16x32_bf16(
              af[mi], bfr[ni], acc[mi][ni], 0, 0, 0);
    }
    if (kt + 1 < KT) WRITEA(nxt);  // A regs arrived during MFMA
    __syncthreads();
  }

  // ---- epilogue: transpose through LDS -> per-INSTRUCTION contiguous stores
  // write: lanes (fr,fq) -> bank (fq*16+fr) mod 32: 2-way (free, m136)
#pragma unroll
  for (int mi = 0; mi < 2; ++mi)
#pragma unroll
    for (int ni = 0; ni < 2; ++ni)
#pragma unroll
      for (int j = 0; j < 4; ++j)
        sm.ep[wr * 32 + mi * 16 + fq * 4 + j][wc * 32 + ni * 16 + fr] = acc[mi][ni][j];
  __syncthreads();

  {
    // 16 lanes per row, 1 float4 each: every store instruction writes
    // 4 rows x 256B fully contiguous (2 full 128B lines per row).
    const int u = t & 15;              // col chunk
    const int rw = t >> 4;             // 0..15
    const int n0 = bn * BN + u * 4;
#pragma unroll
    for (int g = 0; g < 4; ++g) {
      const int r = rw + g * 16;
      const int m = bm * BM + r;
      const int b = m / NPATCH;
      const int s = m - b * NPATCH + 1;  // +1: class token at s=0
      float4 v = *reinterpret_cast<const float4*>(&sm.ep[r][u * 4]);
      float4 bb = *reinterpret_cast<const float4*>(bias + n0);
      float4 pp = *reinterpret_cast<const float4*>(pos + s * Dm + n0);
      v.x += bb.x + pp.x; v.y += bb.y + pp.y; v.z += bb.z + pp.z; v.w += bb.w + pp.w;
      *reinterpret_cast<float4*>(out + (b * SEQn + s) * Dm + n0) = v;
    }
  }
}

}  // namespace

extern "C" void kernel_launch(void* const* d_in, const int* in_sizes, int n_in,
                              void* d_out, int out_size, void* d_ws, size_t ws_size,
                              hipStream_t stream) {
  const float* x = (const float*)d_in[0];
  const float* W = (const float*)d_in[1];
  const float* bias = (const float*)d_in[2];
  const float* pos = (const float*)d_in[3];
  const float* cls = (const float*)d_in[4];
  float* out = (float*)d_out;
  unsigned short* Wt = (unsigned short*)d_ws;  // 768*768*2 = 1.18 MB

  prep_kernel<<<(Ktot / 8) * Ntot / 256 + Bsz * Dm / 256, 256, 0, stream>>>(W, Wt, pos, cls, out);
  gemm_kernel<<<NBLK, 256, 0, stream>>>(x, Wt, bias, pos, out);
}

// Round 5
// 44.790 us; speedup vs baseline: 1.9734x; 1.8119x over previous
//
#include <hip/hip_runtime.h>
#include <hip/hip_bf16.h>

namespace {

constexpr int Bsz = 64, Cch = 3, Himg = 224, Wimg = 224, Ppat = 16;
constexpr int Dm = 768, NPW = 14, NPATCH = 196, SEQn = 197;
constexpr int Mtot = Bsz * NPATCH;   // 12544
constexpr int Ktot = 768, Ntot = 768;
constexpr int BM = 64, BN = 128, BK = 64;
constexpr int MT = Mtot / BM;        // 196
constexpr int NT = Ntot / BN;        // 6
constexpr int KT = Ktot / BK;        // 12
constexpr int NBLK = MT * NT;        // 1176 (divisible by 8)
constexpr int TA = BM * BK;          // 4096 elems = 8 KB
constexpr int TB = BN * BK;          // 8192 elems = 16 KB
constexpr size_t AP_ELEMS = (size_t)MT * KT * TA;          // 9,633,792
constexpr size_t WT_ELEMS = (size_t)NT * KT * TB;          // 589,824
constexpr size_t WS_NEED = (AP_ELEMS + WT_ELEMS) * 2;      // 20,447,232 B
constexpr int WPREP_BLK = (Ktot / 8) * Ntot / 256;         // 288
constexpr int CLS_BLK = Bsz * Dm / 256;                    // 192

typedef __attribute__((ext_vector_type(8))) short bf16x8;
typedef __attribute__((ext_vector_type(4))) float f32x4;

__device__ inline unsigned short f2bf(float f) {
  __bf16 h = (__bf16)f;  // RNE; clang fuses pairs into v_cvt_pk_bf16_f32
  union { __bf16 h; unsigned short u; } c;
  c.h = h;
  return c.u;
}

// ---------------- prepass: patchify x -> Ap, W -> Wt, cls row ---------------
// Ap tile (mt,kt): elem (m',k') at flat (mt*KT+kt)*TA + ((m'*BK+k')^((m'&7)<<3))
// Wt tile (nb,kt): elem (n',k') at flat (nb*KT+kt)*TB + ((n'*BK+k')^((n'&7)<<3))
// Both pre-swizzled so a LINEAR global_load_lds stage yields the swizzled
// LDS image the MFMA ds_read_b128s expect (m173 pattern).
__global__ void prep_kernel(const float* __restrict__ x, const float* __restrict__ W,
                            const float* __restrict__ pos, const float* __restrict__ cls,
                            unsigned short* __restrict__ Ap, unsigned short* __restrict__ Wt,
                            float* __restrict__ out, int nPatchBlk) {
  __shared__ unsigned short tile[TA];
  const int bid = blockIdx.x;
  const int t = threadIdx.x;
  if (bid < nPatchBlk) {  // ---- patchify one 64x64 A-tile
    int mt = bid / KT, kt = bid - mt * KT;
    int ml = t >> 2, ks = t & 3;
    int m = mt * BM + ml;
    int b = m / NPATCH;
    int pidx = m - b * NPATCH;
    int ph = pidx / NPW, pw = pidx - ph * NPW;
    int kbase = kt * BK + ks * 16;            // = c*256 + pi*16
    int c = kbase >> 8, pi = (kbase >> 4) & 15;
    const float* src = x + (((size_t)(b * Cch + c) * Himg + ph * Ppat + pi) * Wimg + pw * Ppat);
#pragma unroll
    for (int j = 0; j < 4; ++j) {
      float4 v = *reinterpret_cast<const float4*>(src + 4 * j);
      int idx = (ml * BK + ks * 16 + 4 * j) ^ ((ml & 7) << 3);
      *reinterpret_cast<ushort4*>(&tile[idx]) =
          make_ushort4(f2bf(v.x), f2bf(v.y), f2bf(v.z), f2bf(v.w));
    }
    __syncthreads();
    const uint4* sp = reinterpret_cast<const uint4*>(tile);
    uint4* dp = reinterpret_cast<uint4*>(Ap + (size_t)bid * TA);
    dp[t] = sp[t];
    dp[t + 256] = sp[t + 256];
  } else if (bid < nPatchBlk + WPREP_BLK) {  // ---- W prep
    int cid = (bid - nPatchBlk) * 256 + t;
    int kc = cid / Ntot;                      // k-chunk of 8 (0..95)
    int n = cid - kc * Ntot;
    int nb = n >> 7;                          // 0..5
    int np = n & 127;
    int kt = kc >> 3;
    int k8 = (kc & 7) * 8;
    unsigned short tmp[8];
#pragma unroll
    for (int j = 0; j < 8; ++j) tmp[j] = f2bf(W[(kc * 8 + j) * Ntot + n]);
    int idx = np * BK + k8;
    int sidx = idx ^ ((np & 7) << 3);
    unsigned short* dst = Wt + (size_t)(nb * KT + kt) * TB + sidx;
    *reinterpret_cast<ushort4*>(dst + 0) = make_ushort4(tmp[0], tmp[1], tmp[2], tmp[3]);
    *reinterpret_cast<ushort4*>(dst + 4) = make_ushort4(tmp[4], tmp[5], tmp[6], tmp[7]);
  } else {  // ---- class-token row (s = 0)
    int i = (bid - nPatchBlk - WPREP_BLK) * 256 + t;
    int b = i / Dm;
    int d = i - b * Dm;
    out[(size_t)b * (SEQn * Dm) + d] = cls[d] + pos[d];
  }
}

// ---------------- pure GEMM: all staging via linear global_load_lds ---------
__global__ __launch_bounds__(256, 3)
void gemm_kernel(const unsigned short* __restrict__ Ap, const unsigned short* __restrict__ Wt,
                 const float* __restrict__ bias, const float* __restrict__ pos,
                 float* __restrict__ out) {
  __shared__ unsigned short A[2][TA];
  __shared__ unsigned short B[2][TB];

  // XCD-chunked bijective swizzle (NBLK % 8 == 0); bn fastest within a chunk.
  const int orig = blockIdx.x;
  const int wg = (orig & 7) * (NBLK / 8) + (orig >> 3);
  const int bm = wg / NT;
  const int bn = wg - bm * NT;

  const int t = threadIdx.x;
  const int lane = t & 63;
  const int wid = t >> 6;              // 4 waves: 2 (M) x 2 (N), each 32x64
  const int wr = wid >> 1, wc = wid & 1;
  const int fr = lane & 15, fq = lane >> 4;

  const unsigned short* aSrc = Ap + (size_t)(bm * KT) * TA + t * 8;
  const unsigned short* bSrc = Wt + (size_t)(bn * KT) * TB + t * 8;

  auto STAGEA = [&](int buf, int kt) {
#pragma unroll
    for (int i = 0; i < 2; ++i)
      __builtin_amdgcn_global_load_lds(
          (const __attribute__((address_space(1))) unsigned int*)(aSrc + kt * TA + i * 2048),
          (__attribute__((address_space(3))) unsigned int*)(&A[buf][t * 8 + i * 2048]),
          16, 0, 0);
  };
  auto STAGEB = [&](int buf, int kt) {
#pragma unroll
    for (int i = 0; i < 4; ++i)
      __builtin_amdgcn_global_load_lds(
          (const __attribute__((address_space(1))) unsigned int*)(bSrc + kt * TB + i * 2048),
          (__attribute__((address_space(3))) unsigned int*)(&B[buf][t * 8 + i * 2048]),
          16, 0, 0);
  };

  f32x4 acc[2][4];
#pragma unroll
  for (int mi = 0; mi < 2; ++mi)
#pragma unroll
    for (int ni = 0; ni < 4; ++ni) acc[mi][ni] = {0.f, 0.f, 0.f, 0.f};

  STAGEA(0, 0);
  STAGEB(0, 0);
  __syncthreads();

  for (int kt = 0; kt < KT; ++kt) {
    const int cur = kt & 1, nxt = cur ^ 1;
    if (kt + 1 < KT) {
      STAGEA(nxt, kt + 1);
      STAGEB(nxt, kt + 1);
    }
#pragma unroll
    for (int ks = 0; ks < 2; ++ks) {
      bf16x8 af[2], bfr[4];
#pragma unroll
      for (int mi = 0; mi < 2; ++mi) {
        int row = wr * 32 + mi * 16 + fr;
        int idx = (row * BK + ks * 32 + fq * 8) ^ ((row & 7) << 3);
        af[mi] = *reinterpret_cast<const bf16x8*>(&A[cur][idx]);
      }
#pragma unroll
      for (int ni = 0; ni < 4; ++ni) {
        int n = wc * 64 + ni * 16 + fr;
        int idx = (n * BK + ks * 32 + fq * 8) ^ ((n & 7) << 3);
        bfr[ni] = *reinterpret_cast<const bf16x8*>(&B[cur][idx]);
      }
#pragma unroll
      for (int mi = 0; mi < 2; ++mi)
#pragma unroll
        for (int ni = 0; ni < 4; ++ni)
          acc[mi][ni] = __builtin_amdgcn_mfma_f32_16x16x32_bf16(
              af[mi], bfr[ni], acc[mi][ni], 0, 0, 0);
    }
    __syncthreads();
  }

  // ---- epilogue: direct stores; per (mi,j) the 4 ni-stores are adjacent and
  // cover 256B contiguous per row (R1-proven: no write amplification).
  const int n0 = bn * BN + wc * 64;
  float bv[4];
#pragma unroll
  for (int ni = 0; ni < 4; ++ni) bv[ni] = bias[n0 + ni * 16 + fr];
#pragma unroll
  for (int mi = 0; mi < 2; ++mi) {
#pragma unroll
    for (int j = 0; j < 4; ++j) {
      int m = bm * BM + wr * 32 + mi * 16 + fq * 4 + j;
      int b = m / NPATCH;
      int s = m - b * NPATCH + 1;  // +1: class token at s=0
      float* orow = out + ((size_t)b * SEQn + s) * Dm + n0;
      const float* prow = pos + (size_t)s * Dm + n0;
#pragma unroll
      for (int ni = 0; ni < 4; ++ni) {
        int d = ni * 16 + fr;
        orow[d] = acc[mi][ni][j] + bv[ni] + prow[d];
      }
    }
  }
}

// ---------------- fallback (ws too small): R2 kernel, stages A in-kernel ----
__global__ __launch_bounds__(512, 6)
void gemm_fb(const float* __restrict__ x, const unsigned short* __restrict__ Wt,
             const float* __restrict__ bias, const float* __restrict__ pos,
             float* __restrict__ out) {
  __shared__ unsigned short As[2][TA];
  __shared__ unsigned short Bs[2][TB];

  const int orig = blockIdx.x;
  const int wg = (orig & 7) * (NBLK / 8) + (orig >> 3);
  const int bm = wg / NT;
  const int bn = wg - bm * NT;

  const int t = threadIdx.x;
  const int lane = t & 63;
  const int wid = t >> 6;              // 8 waves: 2 (M) x 4 (N)
  const int wr = wid >> 2, wc = wid & 3;
  const int fr = lane & 15, fq = lane >> 4;

  const int c4 = t & 15;
  const int r0 = t >> 4;
  int a_base[2];
#pragma unroll
  for (int i = 0; i < 2; ++i) {
    int m = bm * BM + r0 + 32 * i;
    int b = m / NPATCH;
    int pidx = m - b * NPATCH;
    int ph = pidx / NPW;
    int pw = pidx - ph * NPW;
    a_base[i] = ((b * Cch) * Himg + ph * Ppat) * Wimg + pw * Ppat;
  }
  const unsigned short* wt_base = Wt + (size_t)bn * (KT * TB);

  float4 av[2];
  auto LOADA = [&](int kt) {
    int kg = kt * BK + c4 * 4;
    int c = kg >> 8;
    int pi = (kg >> 4) & 15;
    int pj = kg & 15;
    int off = (c * Himg + pi) * Wimg + pj;
#pragma unroll
    for (int i = 0; i < 2; ++i)
      av[i] = *reinterpret_cast<const float4*>(x + a_base[i] + off);
  };
  auto WRITEA = [&](int buf) {
#pragma unroll
    for (int i = 0; i < 2; ++i) {
      int row = r0 + 32 * i;
      int idx = (row * BK + c4 * 4) ^ ((row & 7) << 3);
      ushort4 pk = make_ushort4(f2bf(av[i].x), f2bf(av[i].y), f2bf(av[i].z), f2bf(av[i].w));
      *reinterpret_cast<ushort4*>(&As[buf][idx]) = pk;
    }
  };
  auto STAGEB = [&](int buf, int kt) {
    const unsigned short* src = wt_base + kt * TB + t * 8;
#pragma unroll
    for (int i = 0; i < 2; ++i) {
      __builtin_amdgcn_global_load_lds(
          (const __attribute__((address_space(1))) unsigned int*)(src + i * 4096),
          (__attribute__((address_space(3))) unsigned int*)(&Bs[buf][t * 8 + i * 4096]),
          16, 0, 0);
    }
  };

  f32x4 acc[2][2];
#pragma unroll
  for (int mi = 0; mi < 2; ++mi)
#pragma unroll
    for (int ni = 0; ni < 2; ++ni) acc[mi][ni] = {0.f, 0.f, 0.f, 0.f};

  LOADA(0);
  STAGEB(0, 0);
  WRITEA(0);
  __syncthreads();

  for (int kt = 0; kt < KT; ++kt) {
    const int cur = kt & 1, nxt = cur ^ 1;
    if (kt + 1 < KT) {
      LOADA(kt + 1);
      STAGEB(nxt, kt + 1);
    }
#pragma unroll
    for (int ks = 0; ks < 2; ++ks) {
      bf16x8 af[2], bfr[2];
#pragma unroll
      for (int mi = 0; mi < 2; ++mi) {
        int row = wr * 32 + mi * 16 + fr;
        int idx = (row * BK + ks * 32 + fq * 8) ^ ((row & 7) << 3);
        af[mi] = *reinterpret_cast<const bf16x8*>(&As[cur][idx]);
      }
#pragma unroll
      for (int ni = 0; ni < 2; ++ni) {
        int n = wc * 32 + ni * 16 + fr;
        int idx = (n * BK + ks * 32 + fq * 8) ^ ((n & 7) << 3);
        bfr[ni] = *reinterpret_cast<const bf16x8*>(&Bs[cur][idx]);
      }
#pragma unroll
      for (int mi = 0; mi < 2; ++mi)
#pragma unroll
        for (int ni = 0; ni < 2; ++ni)
          acc[mi][ni] = __builtin_amdgcn_mfma_f32_16x16x32_bf16(
              af[mi], bfr[ni], acc[mi][ni], 0, 0, 0);
    }
    if (kt + 1 < KT) WRITEA(nxt);
    __syncthreads();
  }

  const int n0 = bn * BN + wc * 32;
  float bv[2];
#pragma unroll
  for (int ni = 0; ni < 2; ++ni) bv[ni] = bias[n0 + ni * 16 + fr];
#pragma unroll
  for (int mi = 0; mi < 2; ++mi) {
#pragma unroll
    for (int j = 0; j < 4; ++j) {
      int m = bm * BM + wr * 32 + mi * 16 + fq * 4 + j;
      int b = m / NPATCH;
      int s = m - b * NPATCH + 1;
      float* orow = out + ((size_t)b * SEQn + s) * Dm + n0;
      const float* prow = pos + (size_t)s * Dm + n0;
#pragma unroll
      for (int ni = 0; ni < 2; ++ni) {
        int d = ni * 16 + fr;
        orow[d] = acc[mi][ni][j] + bv[ni] + prow[d];
      }
    }
  }
}

}  // namespace

extern "C" void kernel_launch(void* const* d_in, const int* in_sizes, int n_in,
                              void* d_out, int out_size, void* d_ws, size_t ws_size,
                              hipStream_t stream) {
  const float* x = (const float*)d_in[0];
  const float* W = (const float*)d_in[1];
  const float* bias = (const float*)d_in[2];
  const float* pos = (const float*)d_in[3];
  const float* cls = (const float*)d_in[4];
  float* out = (float*)d_out;

  const bool pure = ws_size >= WS_NEED;
  unsigned short* Ap = (unsigned short*)d_ws;
  unsigned short* Wt = pure ? Ap + AP_ELEMS : Ap;  // fallback: Wt at ws base
  const int nPatchBlk = pure ? MT * KT : 0;        // 2352 or 0

  prep_kernel<<<nPatchBlk + WPREP_BLK + CLS_BLK, 256, 0, stream>>>(
      x, W, pos, cls, Ap, Wt, out, nPatchBlk);
  if (pure)
    gemm_kernel<<<NBLK, 256, 0, stream>>>(Ap, Wt, bias, pos, out);
  else
    gemm_fb<<<NBLK, 512, 0, stream>>>(x, Wt, bias, pos, out);
}